// Round 10
// baseline (135.469 us; speedup 1.0000x reference)
//
#include <hip/hip_runtime.h>
#include <hip/hip_bf16.h>

#define B_TOT 65536
#define S 9
#define D 20
#define DFF 512
#define EPS 1e-5f

typedef short bf16x8 __attribute__((ext_vector_type(8)));
typedef float f32x4 __attribute__((ext_vector_type(4)));

// ws layout (identical to rounds 7-9 — numerically verified):
#define SH_PQKV 0
#define SH_PWOA 2048
#define FL_BQKV 1536
#define FL_BO4 1600
#define SH_PA1 3328
#define SH_PB2 19712
#define PREP_TOTAL (2048 + 1024 + 128 + 16384 + 16384)

__device__ __forceinline__ unsigned short f2bf(float f) {
  union { __hip_bfloat16 h; unsigned short u; } v;
  v.h = __float2bfloat16(f);
  return v.u;
}
__device__ __forceinline__ float bf2f(unsigned short h) {
  union { unsigned u; float f; } v; v.u = ((unsigned)h) << 16; return v.f;
}
__device__ __forceinline__ unsigned cvt2(float a, float b) {
  union { __hip_bfloat162 h; unsigned u; } v;
  v.h = __float22bfloat162_rn(make_float2(a, b));
  return v.u;
}
__device__ __forceinline__ void unpk(unsigned u, float& lo, float& hi) {
  union { unsigned v; float f; } a, b;
  a.v = u << 16; b.v = u & 0xffff0000u;
  lo = a.f; hi = b.f;
}
// exact 10-element bf16 half-row read (20B at 8B-aligned p)
__device__ __forceinline__ void unpack10(const char* p, float* o) {
  uint2 a = *(const uint2*)p;
  uint2 b = *(const uint2*)(p + 8);
  unsigned c = *(const unsigned*)(p + 16);
  unpk(a.x, o[0], o[1]); unpk(a.y, o[2], o[3]);
  unpk(b.x, o[4], o[5]); unpk(b.y, o[6], o[7]);
  unpk(c, o[8], o[9]);
}

__global__ void prep_kernel(const float* __restrict__ Wq, const float* __restrict__ Wk,
                            const float* __restrict__ Wv, const float* __restrict__ Wo,
                            const float* __restrict__ W1, const float* __restrict__ W2,
                            const float* __restrict__ bq, const float* __restrict__ bk,
                            const float* __restrict__ bv, const float* __restrict__ bo,
                            float* __restrict__ wsf) {
  int stride = gridDim.x * blockDim.x;
  unsigned short* P = (unsigned short*)wsf;
  for (int i = blockIdx.x * blockDim.x + threadIdx.x; i < PREP_TOTAL; i += stride) {
    if (i < 2048) {
      int ct = i >> 9, rem = i & 511, l = rem >> 3, jj = rem & 7;
      int g = l >> 4, cl = l & 15;
      int j = ct * 16 + cl, d = 8 * g + jj;
      unsigned short v = 0;
      if (d < 20 && j < 60) {
        int mat = j / 20, jc = j % 20;
        const float* Wsrc = (mat == 0) ? Wq : (mat == 1) ? Wk : Wv;
        v = f2bf(Wsrc[d * 20 + jc]);
      }
      P[SH_PQKV + i] = v;
    } else if (i < 3072) {
      int p = i - 2048;
      int ct = p >> 9, rem = p & 511, l = rem >> 3, jj = rem & 7;
      int g = l >> 4, cl = l & 15;
      int j = ct * 16 + cl, d = 8 * g + jj;
      P[SH_PWOA + p] = (d < 20 && j < 20) ? f2bf(Wo[d * 20 + j]) : (unsigned short)0;
    } else if (i < 3200) {
      int j = i - 3072;  // 0..127
      float v = 0.f;
      if (j < 20) v = bq[j];
      else if (j < 40) v = bk[j - 20];
      else if (j < 60) v = bv[j - 40];
      else if (j >= 64 && j < 84) v = bo[j - 64];
      wsf[FL_BQKV + j] = v;
    } else if (i < 3200 + 16384) {
      int j = i - 3200;
      int frag = j >> 9, rem = j & 511;
      int l = rem >> 3, jj = rem & 7;
      int p = frag & 1, q2 = (frag >> 1) & 3, ch = frag >> 3;
      int g2 = l >> 4, cl2 = l & 15;
      int k = 8 * g2 + jj;
      int f = ch * 128 + q2 * 32 + 8 * (cl2 >> 2) + 4 * p + (cl2 & 3);
      P[SH_PA1 + j] = (k < 20) ? f2bf(W1[k * DFF + f]) : (unsigned short)0;
    } else {
      int j = i - (3200 + 16384);
      int pair = j >> 9, rem = j & 511;
      int l = rem >> 3, jj = rem & 7;
      int g = l >> 4, cl = l & 15;
      int kk = pair >> 1, cc = pair & 1;
      int kg = kk * 32 + 8 * g + jj;
      int d = cc * 16 + cl;
      P[SH_PB2 + j] = (d < 20) ? f2bf(W2[kg * 20 + d]) : (unsigned short)0;
    }
  }
}

// LDS per GROUP (64 rows, 2 waves share): 14336 B; block = 2 groups = 28672 B
//   GX  @0     stride 80: X bf16 rows (contiguous elems 0..19, zeros 20..31) -> y rows
//   GKV @5120  stride 96: k halves @0/@24, v halves @48/@72 (24B halves, 20B data)
//              -> overlay after attention: merged bf16 stride 80 (64B rows)
//   GQ  @11264 stride 48: q halves @0/@24 -> overlay after q dead: ao halves
// byte of element-pair starting at even e within a half-row layout: 2e + 4*(e>=10)
#define GRP_BYTES 14336
#define GX_OFF 0
#define GKV_OFF 5120
#define GQ_OFF 11264

#define FENCE() asm volatile("" ::: "memory")

__global__ __launch_bounds__(256, 2) void encoder_kernel(
    const float* __restrict__ X, const float* __restrict__ ws,
    const float* __restrict__ g1, const float* __restrict__ b1,
    const float* __restrict__ g2, const float* __restrict__ b2,
    float* __restrict__ Out) {
  __shared__ __align__(16) char smem[2 * GRP_BYTES];

  const unsigned short* P16 = (const unsigned short*)ws;
  const unsigned short* PQKV = P16 + SH_PQKV;
  const unsigned short* PWOA = P16 + SH_PWOA;
  const float* BQKV = ws + FL_BQKV;
  const float* BO4 = ws + FL_BO4;
  const unsigned short* PA1 = P16 + SH_PA1;
  const unsigned short* PB2 = P16 + SH_PB2;

  const int tid = threadIdx.x;
  const int lane = tid & 63;
  const int gi = tid >> 7;        // group in block (0,1)
  const int it = tid & 127;       // thread index within group
  const int wg = (tid >> 6) & 1;  // wave within group
  const int ro = it >> 1;         // row 0..63 (63 = pad)
  const int hf = it & 1;          // half of row (heads 2hf..2hf+1, dims 10hf..)
  const int bl = ro / 9;
  const int s = ro - bl * 9;
  const long grp = (long)blockIdx.x * 2 + gi;
  const long bb = grp * 7 + bl;
  const bool active = (bl < 7) && (bb < B_TOT);

  char* G = smem + gi * GRP_BYTES;
  char* GXp = G + GX_OFF;
  char* GKVp = G + GKV_OFF;
  char* GQp = G + GQ_OFF;
  const int cl = lane & 15;
  const int g = lane >> 4;
  const int rt0 = wg * 2;  // this wave's first row-tile of the group's 4
  const f32x4 zero4 = {0.f, 0.f, 0.f, 0.f};

  // ---------------- stage X half-row (contiguous bf16 + zero pad) ------------
  {
    float xh[10];
    if (active) {
      const float* xp = X + bb * (S * D) + s * D + hf * 10;
#pragma unroll
      for (int i = 0; i < 5; ++i) {
        float2 t = *(const float2*)(xp + 2 * i);
        xh[2 * i] = t.x; xh[2 * i + 1] = t.y;
      }
    } else {
#pragma unroll
      for (int i = 0; i < 10; ++i) xh[i] = 0.f;
    }
    unsigned u0 = cvt2(xh[0], xh[1]), u1 = cvt2(xh[2], xh[3]), u2 = cvt2(xh[4], xh[5]),
             u3 = cvt2(xh[6], xh[7]), u4 = cvt2(xh[8], xh[9]);
    char* r = GXp + ro * 80;
    if (hf == 0) {
      *(uint2*)(r) = make_uint2(u0, u1);
      *(uint2*)(r + 8) = make_uint2(u2, u3);
      *(unsigned*)(r + 16) = u4;
      *(uint2*)(r + 40) = make_uint2(0u, 0u);
    } else {
      *(unsigned*)(r + 20) = u0;
      *(uint2*)(r + 24) = make_uint2(u1, u2);
      *(uint2*)(r + 32) = make_uint2(u3, u4);
      *(uint4*)(r + 48) = make_uint4(0u, 0u, 0u, 0u);
    }
  }
  FENCE();  // rows 32wg..32wg+31 staged by this wave; frags below read same rows

  // ---------------- X B-frags (own-wave rows only) ----------------------------
  bf16x8 xfB[2];
#pragma unroll
  for (int rt = 0; rt < 2; ++rt)
    xfB[rt] = *(const bf16x8*)(GXp + ((rt0 + rt) * 16 + cl) * 80 + g * 16);
  FENCE();

  // ---------------- QKV MFMA (swapped), half-layout dword scatter -------------
#pragma unroll
  for (int ct = 0; ct < 4; ++ct) {
    bf16x8 wf = *(const bf16x8*)(PQKV + (size_t)(ct * 64 + lane) * 8);
    float4 bq4 = *(const float4*)(BQKV + ct * 16 + 4 * g);
    const int qd = ct * 4 + g;
    const int mat = (qd >= 10) ? 2 : ((qd >= 5) ? 1 : 0);
    const int jc4 = qd - 5 * mat;
    const int e0 = 4 * jc4;
    const bool qv = qd < 15;
    const int b0 = 2 * e0 + ((e0 >= 10) ? 4 : 0);
    const int b1o = 2 * (e0 + 2) + (((e0 + 2) >= 10) ? 4 : 0);
#pragma unroll
    for (int rt = 0; rt < 2; ++rt) {
      f32x4 dd = __builtin_amdgcn_mfma_f32_16x16x32_bf16(wf, xfB[rt], zero4, 0, 0, 0);
      if (qv) {
        const int row = (rt0 + rt) * 16 + cl;
        unsigned w0 = cvt2(dd[0] + bq4.x, dd[1] + bq4.y);
        unsigned w1 = cvt2(dd[2] + bq4.z, dd[3] + bq4.w);
        char* base = (mat == 0) ? (GQp + row * 48)
                                : (GKVp + row * 96 + ((mat == 2) ? 48 : 0));
        *(unsigned*)(base + b0) = w0;
        *(unsigned*)(base + b1o) = w1;
      }
    }
  }
  __syncthreads();  // B2: scatters (both waves) -> attention reads

  // ---------------- attention: thread = (row, 2 heads) ------------------------
  float ctx10[10];
  if (active) {
    float q10[10];
    unpack10(GQp + ro * 48 + 24 * hf, q10);
    float sc[2][9];
#pragma unroll
    for (int t = 0; t < 9; ++t) {
      float kt[10];
      unpack10(GKVp + (bl * 9 + t) * 96 + 24 * hf, kt);
#pragma unroll
      for (int hh = 0; hh < 2; ++hh) {
        float d0 = q10[5 * hh + 0] * kt[5 * hh + 0] + q10[5 * hh + 1] * kt[5 * hh + 1];
        float d1 = q10[5 * hh + 2] * kt[5 * hh + 2] + q10[5 * hh + 3] * kt[5 * hh + 3];
        sc[hh][t] = d0 + d1 + q10[5 * hh + 4] * kt[5 * hh + 4];
      }
    }
    float inv2[2];
#pragma unroll
    for (int hh = 0; hh < 2; ++hh) {
      float mx = sc[hh][0];
#pragma unroll
      for (int t = 1; t < 9; ++t) mx = fmaxf(mx, sc[hh][t]);
      float sum = 0.f;
#pragma unroll
      for (int t = 0; t < 9; ++t) {
        sc[hh][t] = __expf((sc[hh][t] - mx) * (1.0f / 3.0f));
        sum += sc[hh][t];
      }
      inv2[hh] = 1.0f / sum;
    }
#pragma unroll
    for (int i = 0; i < 10; ++i) ctx10[i] = 0.f;
#pragma unroll
    for (int t = 0; t < 9; ++t) {
      float vt[10];
      unpack10(GKVp + (bl * 9 + t) * 96 + 48 + 24 * hf, vt);
#pragma unroll
      for (int hh = 0; hh < 2; ++hh)
#pragma unroll
        for (int dd = 0; dd < 5; ++dd)
          ctx10[5 * hh + dd] += sc[hh][t] * vt[5 * hh + dd];
    }
#pragma unroll
    for (int hh = 0; hh < 2; ++hh)
#pragma unroll
      for (int dd = 0; dd < 5; ++dd)
        ctx10[5 * hh + dd] *= inv2[hh];
  }
  __syncthreads();  // B3: all k/v reads done -> merged overlay writes

  // ---------------- merged-ctx scatter (transpose quirk) + pads ---------------
  if (active) {
#pragma unroll
    for (int hh = 0; hh < 2; ++hh)
#pragma unroll
      for (int dh = 0; dh < 5; ++dh) {
        int w = 5 * (2 * hf + hh) + dh;
        int m = 9 * w + s;              // m < 180
        int rr = (m * 3277) >> 16;      // m/20
        int col = m - 20 * rr;
        *(unsigned short*)(GKVp + (bl * 9 + rr) * 80 + col * 2) = f2bf(ctx10[5 * hh + dh]);
      }
  } else {
    char* r = GKVp + ro * 80;
    if (hf == 0) {
      *(uint2*)(r) = make_uint2(0u, 0u);
      *(uint2*)(r + 8) = make_uint2(0u, 0u);
      *(unsigned*)(r + 16) = 0u;
    } else {
      *(unsigned*)(r + 20) = 0u;
      *(uint2*)(r + 24) = make_uint2(0u, 0u);
      *(uint2*)(r + 32) = make_uint2(0u, 0u);
    }
  }
  {
    char* r = GKVp + ro * 80;
    if (hf == 0) *(uint2*)(r + 40) = make_uint2(0u, 0u);
    else *(uint4*)(r + 48) = make_uint4(0u, 0u, 0u, 0u);
  }
  __syncthreads();  // B4: merged rows (written by mixed waves) -> Wo frag reads

  // ---------------- Wo MFMA (swapped), ao scatter to GQ overlay ---------------
  bf16x8 mfB[2];
#pragma unroll
  for (int rt = 0; rt < 2; ++rt)
    mfB[rt] = *(const bf16x8*)(GKVp + ((rt0 + rt) * 16 + cl) * 80 + g * 16);
  FENCE();  // ao writes go to GQ (disjoint from merged) — no barrier needed
#pragma unroll
  for (int ct = 0; ct < 2; ++ct) {
    bf16x8 wof = *(const bf16x8*)(PWOA + (size_t)(ct * 64 + lane) * 8);
    float4 bo4 = *(const float4*)(BO4 + ct * 16 + 4 * g);
    const int qd = ct * 4 + g;
    const bool qv = qd < 5;
    const int e0 = 4 * qd;
    const int b0 = 2 * e0 + ((e0 >= 10) ? 4 : 0);
    const int b1o = 2 * (e0 + 2) + (((e0 + 2) >= 10) ? 4 : 0);
#pragma unroll
    for (int rt = 0; rt < 2; ++rt) {
      f32x4 dd = __builtin_amdgcn_mfma_f32_16x16x32_bf16(wof, mfB[rt], zero4, 0, 0, 0);
      if (qv) {
        const int row = (rt0 + rt) * 16 + cl;
        unsigned w0 = cvt2(dd[0] + bo4.x, dd[1] + bo4.y);
        unsigned w1 = cvt2(dd[2] + bo4.z, dd[3] + bo4.w);
        *(unsigned*)(GQp + row * 48 + b0) = w0;
        *(unsigned*)(GQp + row * 48 + b1o) = w1;
      }
    }
  }
  FENCE();  // ao rows 32wg..+31 scattered by own wave; LN1 reads own row

  // ---------------- LN1 (pair reduce) + y stage -------------------------------
  {
    float yh[10];
    if (active) {
      float ah[10];
      unpack10(GQp + ro * 48 + 24 * hf, ah);
      float xh[10];
      const char* xr = GXp + ro * 80;
      if (hf == 0) {
        uint2 a = *(const uint2*)(xr);
        uint2 b = *(const uint2*)(xr + 8);
        unsigned c = *(const unsigned*)(xr + 16);
        unpk(a.x, xh[0], xh[1]); unpk(a.y, xh[2], xh[3]);
        unpk(b.x, xh[4], xh[5]); unpk(b.y, xh[6], xh[7]);
        unpk(c, xh[8], xh[9]);
      } else {
        unsigned a = *(const unsigned*)(xr + 20);
        uint2 b = *(const uint2*)(xr + 24);
        uint2 c = *(const uint2*)(xr + 32);
        unpk(a, xh[0], xh[1]); unpk(b.x, xh[2], xh[3]); unpk(b.y, xh[4], xh[5]);
        unpk(c.x, xh[6], xh[7]); unpk(c.y, xh[8], xh[9]);
      }
      float z[10];
      float t0 = 0.f;
#pragma unroll
      for (int i = 0; i < 10; ++i) { z[i] = ah[i] + xh[i]; t0 += z[i]; }
      t0 += __shfl_xor(t0, 1);
      float mean = t0 * (1.0f / 20.0f);
      float var = 0.f;
#pragma unroll
      for (int i = 0; i < 10; ++i) { z[i] -= mean; var += z[i] * z[i]; }
      var += __shfl_xor(var, 1);
      float rs = rsqrtf(var * (1.0f / 20.0f) + EPS);
#pragma unroll
      for (int i = 0; i < 10; ++i) yh[i] = z[i] * rs * g1[10 * hf + i] + b1[10 * hf + i];
    } else {
#pragma unroll
      for (int i = 0; i < 10; ++i) yh[i] = 0.f;
    }
    unsigned u0 = cvt2(yh[0], yh[1]), u1 = cvt2(yh[2], yh[3]), u2 = cvt2(yh[4], yh[5]),
             u3 = cvt2(yh[6], yh[7]), u4 = cvt2(yh[8], yh[9]);
    char* r = GXp + ro * 80;
    if (hf == 0) {
      *(uint2*)(r) = make_uint2(u0, u1);
      *(uint2*)(r + 8) = make_uint2(u2, u3);
      *(unsigned*)(r + 16) = u4;
    } else {
      *(unsigned*)(r + 20) = u0;
      *(uint2*)(r + 24) = make_uint2(u1, u2);
      *(uint2*)(r + 32) = make_uint2(u3, u4);
    }
    // bytes 40..63 still zero from X stage
  }
  FENCE();  // y rows 32wg..+31 staged by own wave; ytf frags read same rows

  // ---------------- FFN via MFMA (register-resident H, verified flow) ---------
  bf16x8 ytf[2];
#pragma unroll
  for (int rt = 0; rt < 2; ++rt)
    ytf[rt] = *(const bf16x8*)(GXp + ((rt0 + rt) * 16 + cl) * 80 + g * 16);

  f32x4 acc[2][2];
#pragma unroll
  for (int rt = 0; rt < 2; ++rt) { acc[rt][0] = zero4; acc[rt][1] = zero4; }

  for (int ch = 0; ch < 4; ++ch) {
#pragma unroll
    for (int q2 = 0; q2 < 4; ++q2) {
      const int fb = ch * 8 + q2 * 2;
      bf16x8 aw0 = *(const bf16x8*)(PA1 + (size_t)(fb * 64 + lane) * 8);
      bf16x8 aw1 = *(const bf16x8*)(PA1 + (size_t)((fb + 1) * 64 + lane) * 8);
      bf16x8 bw0 = *(const bf16x8*)(PB2 + (size_t)(fb * 64 + lane) * 8);
      bf16x8 bw1 = *(const bf16x8*)(PB2 + (size_t)((fb + 1) * 64 + lane) * 8);
#pragma unroll
      for (int rt = 0; rt < 2; ++rt) {
        f32x4 d0 = __builtin_amdgcn_mfma_f32_16x16x32_bf16(aw0, ytf[rt], zero4, 0, 0, 0);
        f32x4 d1 = __builtin_amdgcn_mfma_f32_16x16x32_bf16(aw1, ytf[rt], zero4, 0, 0, 0);
        union { bf16x8 v; unsigned uu[4]; } af;
        af.uu[0] = cvt2(fmaxf(d0[0], 0.f), fmaxf(d0[1], 0.f));
        af.uu[1] = cvt2(fmaxf(d0[2], 0.f), fmaxf(d0[3], 0.f));
        af.uu[2] = cvt2(fmaxf(d1[0], 0.f), fmaxf(d1[1], 0.f));
        af.uu[3] = cvt2(fmaxf(d1[2], 0.f), fmaxf(d1[3], 0.f));
        acc[rt][0] = __builtin_amdgcn_mfma_f32_16x16x32_bf16(af.v, bw0, acc[rt][0], 0, 0, 0);
        acc[rt][1] = __builtin_amdgcn_mfma_f32_16x16x32_bf16(af.v, bw1, acc[rt][1], 0, 0, 0);
      }
    }
  }

  // ---------------- LN2 in fragment space + store -----------------------------
  const float gg0 = g2[cl], bb0 = b2[cl];
  const float gg1 = (cl < 4) ? g2[16 + cl] : 0.f;
  const float bb1 = (cl < 4) ? b2[16 + cl] : 0.f;
  const long wrbase = grp * 63;
  const long total_rows = (long)B_TOT * S;

#pragma unroll
  for (int rt = 0; rt < 2; ++rt) {
#pragma unroll
    for (int r = 0; r < 4; ++r) {
      const int rrow = (rt0 + rt) * 16 + 4 * g + r;
      float y0 = bf2f(*(const unsigned short*)(GXp + rrow * 80 + cl * 2));
      float y1 = (cl < 4) ? bf2f(*(const unsigned short*)(GXp + rrow * 80 + 32 + cl * 2)) : 0.f;
      float z0 = acc[rt][0][r] + y0;
      float z1 = acc[rt][1][r] + y1;
      float t = z0 + ((cl < 4) ? z1 : 0.f);
      t += __shfl_xor(t, 1, 16);
      t += __shfl_xor(t, 2, 16);
      t += __shfl_xor(t, 4, 16);
      t += __shfl_xor(t, 8, 16);
      float mean = t * (1.0f / 20.0f);
      float c0 = z0 - mean, c1 = z1 - mean;
      float vt = c0 * c0 + ((cl < 4) ? c1 * c1 : 0.f);
      vt += __shfl_xor(vt, 1, 16);
      vt += __shfl_xor(vt, 2, 16);
      vt += __shfl_xor(vt, 4, 16);
      vt += __shfl_xor(vt, 8, 16);
      float rs = rsqrtf(vt * (1.0f / 20.0f) + EPS);
      const long grow = wrbase + rrow;
      if (rrow < 63 && grow < total_rows) {
        Out[grow * 20 + cl] = c0 * rs * gg0 + bb0;
        if (cl < 4) Out[grow * 20 + 16 + cl] = c1 * rs * gg1 + bb1;
      }
    }
  }
}

extern "C" void kernel_launch(void* const* d_in, const int* in_sizes, int n_in,
                              void* d_out, int out_size, void* d_ws, size_t ws_size,
                              hipStream_t stream) {
  const float* X  = (const float*)d_in[0];
  const float* Wq = (const float*)d_in[1];
  const float* bq = (const float*)d_in[2];
  const float* Wk = (const float*)d_in[3];
  const float* bk = (const float*)d_in[4];
  const float* Wv = (const float*)d_in[5];
  const float* bv = (const float*)d_in[6];
  const float* Wo = (const float*)d_in[7];
  const float* bo = (const float*)d_in[8];
  const float* g1 = (const float*)d_in[9];
  const float* b1 = (const float*)d_in[10];
  const float* W1 = (const float*)d_in[11];
  const float* W2 = (const float*)d_in[12];
  const float* g2 = (const float*)d_in[13];
  const float* b2 = (const float*)d_in[14];
  float* Out = (float*)d_out;
  float* ws = (float*)d_ws;

  prep_kernel<<<144, 256, 0, stream>>>(Wq, Wk, Wv, Wo, W1, W2, bq, bk, bv, bo, ws);

  // block = 256 threads = 2 groups x (7 batch elems, 2 waves each)
  int nblocks = (B_TOT + 13) / 14;
  encoder_kernel<<<nblocks, 256, 0, stream>>>(X, ws, g1, b1, g2, b2, Out);
}